// Round 20
// baseline (2223.331 us; speedup 1.0000x reference)
//
#include <hip/hip_runtime.h>
#include <hip/hip_bf16.h>

#define NCB 16
#define CS 256
#define HD 384
#define PD 2048
#define NROW 16384
#define NH 6144      // NCB*HD
#define LSR 5760     // (NCB-1)*HD  rows of linear_self
#define LSC 3840     // (NCB-1)*CS  cols of linear_self
#define SA_ROWS 32
#define SA_NBLK (NROW / SA_ROWS)   // 512
#define GK 32                      // 32 K-steps of 64 bytes for fp8 gemm1

typedef __bf16 bf16x8 __attribute__((ext_vector_type(8)));
typedef float f32x4 __attribute__((ext_vector_type(4)));
typedef int int4v __attribute__((ext_vector_type(4)));
typedef int int2v __attribute__((ext_vector_type(2)));

__device__ __forceinline__ unsigned short f2bf(float f) {
  unsigned u = __builtin_bit_cast(unsigned, f);
  u = (u + 0x7fffu + ((u >> 16) & 1u)) >> 16;
  return (unsigned short)u;
}
__device__ __forceinline__ float bf2f(unsigned short h) {
  unsigned u = ((unsigned)h) << 16;
  return __builtin_bit_cast(float, u);
}
__device__ __forceinline__ unsigned char f2fp8(float f) {
  return (unsigned char)__builtin_amdgcn_cvt_pk_fp8_f32(f, f, 0, false);
}
__device__ __forceinline__ long lo64(int4v v) {
  int2v t; t[0] = v[0]; t[1] = v[1];
  return __builtin_bit_cast(long, t);
}
__device__ __forceinline__ long hi64(int4v v) {
  int2v t; t[0] = v[2]; t[1] = v[3];
  return __builtin_bit_cast(long, t);
}

__device__ __forceinline__ void gload16(void* lds, const void* g) {
  __builtin_amdgcn_global_load_lds(
      (const __attribute__((address_space(1))) unsigned int*)g,
      (__attribute__((address_space(3))) unsigned int*)lds, 16, 0, 0);
}

// ---------------- fp32 -> fp8 e4m3 conversion (8 elements/thread/iter) ----------------
__global__ void k_f2b8(const float* __restrict__ in, unsigned* __restrict__ out, int n8) {
  for (int i = blockIdx.x * 256 + threadIdx.x; i < n8; i += gridDim.x * 256) {
    float4 a = ((const float4*)in)[i * 2];
    float4 b = ((const float4*)in)[i * 2 + 1];
    unsigned lo = __builtin_amdgcn_cvt_pk_fp8_f32(a.x, a.y, 0, false);
    lo = __builtin_amdgcn_cvt_pk_fp8_f32(a.z, a.w, lo, true);
    unsigned hi = __builtin_amdgcn_cvt_pk_fp8_f32(b.x, b.y, 0, false);
    hi = __builtin_amdgcn_cvt_pk_fp8_f32(b.z, b.w, hi, true);
    uint2 o = {lo, hi};
    ((uint2*)out)[i] = o;
  }
}

// ---------------- transpose linear_self (5760x3840 f32) -> T (3840x5760 fp8 e4m3) ----------------
__global__ __launch_bounds__(256) void k_transpose(const float* __restrict__ LS,
                                                   unsigned char* __restrict__ T) {
  __shared__ float tile[32][33];
  int tx = threadIdx.x & 31, ty = threadIdx.x >> 5;
  int c0 = blockIdx.x * 32;  // col of LS = row of T
  int r0 = blockIdx.y * 32;  // row of LS = col of T
  for (int i = ty; i < 32; i += 8)
    tile[i][tx] = LS[(size_t)(r0 + i) * LSC + c0 + tx];
  __syncthreads();
  const int i = threadIdx.x >> 3;        // T-row offset 0..31
  const int q = (threadIdx.x & 7) * 4;   // r-offset 0,4,..,28
  unsigned u = __builtin_amdgcn_cvt_pk_fp8_f32(tile[q][i], tile[q + 1][i], 0, false);
  u = __builtin_amdgcn_cvt_pk_fp8_f32(tile[q + 2][i], tile[q + 3][i], u, true);
  *(unsigned*)(T + (size_t)(c0 + i) * LSR + r0 + q) = u;
}

// ---------------- count valid[:,0] ----------------
__global__ void k_count(const int* __restrict__ ci, float* __restrict__ out) {
  int n = blockIdx.x * 256 + threadIdx.x;
  float v = (n < NROW && ci[(size_t)n * NCB] >= 0) ? 1.f : 0.f;
  #pragma unroll
  for (int m = 1; m < 64; m <<= 1) v += __shfl_xor(v, m);
  if ((threadIdx.x & 63) == 0) atomicAdd(out + 1, v);
}

// ---------------- GEMM1 (fp8): 256x128 tile, BK=64, dbuf 48KB, 3 blocks/CU ----------------
// r19 core; H stores now CACHED (not NT) so L2 merges the 16B quarter-line
// segments into full 64B lines (kills the 4x write amplification); 3 blocks/CU
// (48KB LDS x3 <= 160KB; regs tiny) for deeper cross-block overlap.
__global__ __launch_bounds__(512, 6) void k_gemm1(
    const unsigned char* __restrict__ A,   // predictor fp8 [NROW][PD]
    const unsigned char* __restrict__ B,   // W1 fp8 [NH][PD]
    const float* __restrict__ b1,
    unsigned char* __restrict__ H) {       // out [NROW][NH] fp8 (pre-activation)
  __shared__ int4v Al[2][1024];   // [buf][row(256)*4 + pc]  16KB/buf
  __shared__ int4v Bl[2][512];    // [buf][row(128)*4 + pc]   8KB/buf

  const int tid = threadIdx.x;
  const int lane = tid & 63;
  const int w = tid >> 6;             // 0..7
  const int wr = w >> 1, wc = w & 1;  // wave grid 4(M) x 2(N), wave = 64x64
  const int l15 = lane & 15, hi = lane >> 4;
  const int w64 = tid & ~63;

  // XCD swizzle: grid 3072 = 64 mt x 48 nt; each XCD owns 6 nt (1.5MB B -> L2)
  const int bid = blockIdx.x;
  const int xcd = bid & 7, p = bid >> 3;   // p in [0,384)
  const int nt = xcd * 6 + p % 6;
  const int mt = p / 6;
  const int tm = mt * 256, tn = nt * 128;

  f32x4 acc[4][4] = {};

  auto STAGE = [&](int buf, int t) {
    const int kb = t * 64;   // byte offset along K
    #pragma unroll
    for (int g = 0; g < 2; ++g) {   // A: 1024 granules
      const int slot = g * 512 + tid;
      const int row = slot >> 2;
      const int lc = (slot & 3) ^ ((row >> 1) & 3);
      gload16(&Al[buf][g * 512 + w64], A + (size_t)(tm + row) * PD + kb + lc * 16);
    }
    {                                // B: 512 granules
      const int row = tid >> 2;
      const int lc = (tid & 3) ^ ((row >> 1) & 3);
      gload16(&Bl[buf][w64], B + (size_t)(tn + row) * PD + kb + lc * 16);
    }
  };

  STAGE(0, 0);
  asm volatile("s_waitcnt vmcnt(0)" ::: "memory");
  __builtin_amdgcn_s_barrier();

  for (int t = 0; t < GK; ++t) {
    const int buf = t & 1;
    // frag reads (swizzled, b128 = K=64 fp8)
    int4v af[4], bfr[4];
    #pragma unroll
    for (int mi = 0; mi < 4; ++mi) {
      const int row = wr * 64 + mi * 16 + l15;
      af[mi] = Al[buf][row * 4 + (hi ^ ((row >> 1) & 3))];
    }
    #pragma unroll
    for (int ni = 0; ni < 4; ++ni) {
      const int row = wc * 64 + ni * 16 + l15;
      bfr[ni] = Bl[buf][row * 4 + (hi ^ ((row >> 1) & 3))];
    }
    if (t + 1 < GK) STAGE(buf ^ 1, t + 1);   // next-window loads in flight
    // (no barrier here — cross-wave/cross-block read-vs-MFMA overlap)
    __builtin_amdgcn_s_setprio(1);
    #pragma unroll
    for (int mi = 0; mi < 4; ++mi) {
      const long a1 = lo64(af[mi]);
      #pragma unroll
      for (int ni = 0; ni < 4; ++ni)
        acc[mi][ni] = __builtin_amdgcn_mfma_f32_16x16x32_fp8_fp8(
            a1, lo64(bfr[ni]), acc[mi][ni], 0, 0, 0);
    }
    #pragma unroll
    for (int mi = 0; mi < 4; ++mi) {
      const long a2 = hi64(af[mi]);
      #pragma unroll
      for (int ni = 0; ni < 4; ++ni)
        acc[mi][ni] = __builtin_amdgcn_mfma_f32_16x16x32_fp8_fp8(
            a2, hi64(bfr[ni]), acc[mi][ni], 0, 0, 0);
    }
    __builtin_amdgcn_s_setprio(0);
    if (t + 1 < GK) {
      asm volatile("s_waitcnt vmcnt(0)" ::: "memory");
      __builtin_amdgcn_s_barrier();
    }
  }

  // epilogue: bias + fp8 store (cached: L2 merges quarter-line segments)
  #pragma unroll
  for (int ni = 0; ni < 4; ++ni) {
    const int col = tn + wc * 64 + ni * 16 + l15;
    const float bb = b1[col];
    #pragma unroll
    for (int mi = 0; mi < 4; ++mi)
      #pragma unroll
      for (int reg = 0; reg < 4; ++reg) {
        const int row = tm + wr * 64 + mi * 16 + hi * 4 + reg;
        H[(size_t)row * NH + col] = f2fp8(acc[mi][ni][reg] + bb);
      }
  }
}

// ---------------- self-pred gather: branch-free unrolled, fp8 T + fp8 H ----------------
template <int KM>
__device__ __forceinline__ void gather_chunk(
    const unsigned char* __restrict__ T, const int* idxrow,
    int oo, int bbv, float v[8]) {
  #pragma unroll
  for (int kc = 0; kc < KM; ++kc) {
    int c = idxrow[kc];
    float m = (c >= 0 && kc <= bbv) ? 1.f : 0.f;
    int cc = c < 0 ? 0 : (c >= CS ? CS - 1 : c);
    int2 tv = *(const int2*)(T + (size_t)(kc * CS + cc) * LSR + oo);  // 8 fp8
    float f[8];
    f[0] = __builtin_amdgcn_cvt_f32_fp8(tv.x, 0);
    f[1] = __builtin_amdgcn_cvt_f32_fp8(tv.x, 1);
    f[2] = __builtin_amdgcn_cvt_f32_fp8(tv.x, 2);
    f[3] = __builtin_amdgcn_cvt_f32_fp8(tv.x, 3);
    f[4] = __builtin_amdgcn_cvt_f32_fp8(tv.y, 0);
    f[5] = __builtin_amdgcn_cvt_f32_fp8(tv.y, 1);
    f[6] = __builtin_amdgcn_cvt_f32_fp8(tv.y, 2);
    f[7] = __builtin_amdgcn_cvt_f32_fp8(tv.y, 3);
    #pragma unroll
    for (int e = 0; e < 8; ++e) v[e] = fmaf(m, f[e], v[e]);
  }
}

// grid = dim3(3, SA_NBLK): x = 2048-col stripe, y = 32-row block.
__global__ __launch_bounds__(256) void k_selfadd(
    unsigned char* __restrict__ H,         // [NROW][NH] fp8, in-place
    const unsigned char* __restrict__ T,   // [LSC][LSR] fp8 (linear_self^T)
    const int* __restrict__ ci,
    float* __restrict__ partials) {        // [2][SA_NBLK][NH]
  __shared__ int idxs[SA_ROWS][NCB];
  const int tid = threadIdx.x;
  const int row0 = blockIdx.y * SA_ROWS;
  const int sx = blockIdx.x;               // 0..2, block-uniform
  for (int i = tid; i < SA_ROWS * NCB; i += 256)
    idxs[i >> 4][i & 15] = ci[(size_t)(row0 + (i >> 4)) * NCB + (i & 15)];
  __syncthreads();

  const int col0 = sx * 2048 + tid * 8;
  const int o = col0 - HD;
  const int oo = o < 0 ? 0 : o;
  const int bb = o < 0 ? -1 : o / HD;

  float cs[8] = {0}, cq[8] = {0};

  for (int rr = 0; rr < SA_ROWS; ++rr) {
    const size_t ro = (size_t)(row0 + rr) * NH;
    int2v hv = __builtin_nontemporal_load((const int2v*)(H + ro + col0));
    float v[8];
    v[0] = __builtin_amdgcn_cvt_f32_fp8(hv[0], 0);
    v[1] = __builtin_amdgcn_cvt_f32_fp8(hv[0], 1);
    v[2] = __builtin_amdgcn_cvt_f32_fp8(hv[0], 2);
    v[3] = __builtin_amdgcn_cvt_f32_fp8(hv[0], 3);
    v[4] = __builtin_amdgcn_cvt_f32_fp8(hv[1], 0);
    v[5] = __builtin_amdgcn_cvt_f32_fp8(hv[1], 1);
    v[6] = __builtin_amdgcn_cvt_f32_fp8(hv[1], 2);
    v[7] = __builtin_amdgcn_cvt_f32_fp8(hv[1], 3);
    switch (sx) {
      case 0: gather_chunk<5>(T, idxs[rr], oo, bb, v); break;
      case 1: gather_chunk<10>(T, idxs[rr], oo, bb, v); break;
      default: gather_chunk<15>(T, idxs[rr], oo, bb, v); break;
    }
    float x[8];
    #pragma unroll
    for (int e = 0; e < 8; ++e) x[e] = fmaxf(v[e], 0.f);
    int2v ov;
    unsigned w0 = __builtin_amdgcn_cvt_pk_fp8_f32(x[0], x[1], 0, false);
    w0 = __builtin_amdgcn_cvt_pk_fp8_f32(x[2], x[3], w0, true);
    unsigned w1 = __builtin_amdgcn_cvt_pk_fp8_f32(x[4], x[5], 0, false);
    w1 = __builtin_amdgcn_cvt_pk_fp8_f32(x[6], x[7], w1, true);
    ov[0] = (int)w0; ov[1] = (int)w1;
    float xr0 = __builtin_amdgcn_cvt_f32_fp8(w0, 0);
    float xr1 = __builtin_amdgcn_cvt_f32_fp8(w0, 1);
    float xr2 = __builtin_amdgcn_cvt_f32_fp8(w0, 2);
    float xr3 = __builtin_amdgcn_cvt_f32_fp8(w0, 3);
    float xr4 = __builtin_amdgcn_cvt_f32_fp8(w1, 0);
    float xr5 = __builtin_amdgcn_cvt_f32_fp8(w1, 1);
    float xr6 = __builtin_amdgcn_cvt_f32_fp8(w1, 2);
    float xr7 = __builtin_amdgcn_cvt_f32_fp8(w1, 3);
    cs[0] += xr0; cq[0] += xr0 * xr0;
    cs[1] += xr1; cq[1] += xr1 * xr1;
    cs[2] += xr2; cq[2] += xr2 * xr2;
    cs[3] += xr3; cq[3] += xr3 * xr3;
    cs[4] += xr4; cq[4] += xr4 * xr4;
    cs[5] += xr5; cq[5] += xr5 * xr5;
    cs[6] += xr6; cq[6] += xr6 * xr6;
    cs[7] += xr7; cq[7] += xr7 * xr7;
    __builtin_nontemporal_store(ov, (int2v*)(H + ro + col0));
  }

  float* Ps = partials + (size_t)blockIdx.y * NH + col0;
  float* Pq = partials + (size_t)(SA_NBLK + blockIdx.y) * NH + col0;
  float4 a = {cs[0], cs[1], cs[2], cs[3]};
  float4 b4 = {cs[4], cs[5], cs[6], cs[7]};
  *(float4*)Ps = a; *(float4*)(Ps + 4) = b4;
  float4 c4 = {cq[0], cq[1], cq[2], cq[3]};
  float4 d4 = {cq[4], cq[5], cq[6], cq[7]};
  *(float4*)Pq = c4; *(float4*)(Pq + 4) = d4;
}

// ---------------- reduce partials -> colsum/colsq ----------------
__global__ void k_red(const float* __restrict__ partials,
                      float* __restrict__ colsum, float* __restrict__ colsq) {
  int j = blockIdx.x * 256 + threadIdx.x;
  const float* Ps = partials;
  const float* Pq = partials + (size_t)SA_NBLK * NH;
  float s = 0.f, q = 0.f;
  const int b0 = blockIdx.y * (SA_NBLK / 8), b1 = b0 + SA_NBLK / 8;
  for (int by = b0; by < b1; ++by) {
    s += Ps[(size_t)by * NH + j];
    q += Pq[(size_t)by * NH + j];
  }
  atomicAdd(colsum + j, s);
  atomicAdd(colsq + j, q);
}

// ---------------- BN params ----------------
__global__ void k_bn(const float* __restrict__ colsum, const float* __restrict__ colsq,
                     const float* __restrict__ gamma, const float* __restrict__ beta,
                     float* __restrict__ scale, float* __restrict__ shift) {
  int j = blockIdx.x * 256 + threadIdx.x;
  if (j >= NH) return;
  float mean = colsum[j] * (1.f / NROW);
  float var = colsq[j] * (1.f / NROW) - mean * mean;
  var = fmaxf(var, 0.f);
  float rs = rsqrtf(var + 1e-5f);
  float g = gamma[j] * rs;
  scale[j] = g;
  shift[j] = beta[j] - mean * g;
}

// ---------------- fold BN into linear2/bias2 (fp8 L2b) ----------------
__global__ __launch_bounds__(128) void k_fold(
    const float* __restrict__ L2, const float* __restrict__ bias2,
    const float* __restrict__ scale, const float* __restrict__ shift,
    unsigned char* __restrict__ L2b8, float* __restrict__ bias2p) {
  __shared__ float red[2];
  int kc = blockIdx.x;        // k*256 + c
  int k = kc >> 8;
  size_t off = (size_t)kc * HD;
  float a = 0.f;
  for (int h = threadIdx.x; h < HD; h += 128) {
    float wv = L2[off + h];
    int jh = k * HD + h;
    L2b8[off + h] = f2fp8(wv * scale[jh]);
    a += wv * shift[jh];
  }
  #pragma unroll
  for (int m = 1; m < 64; m <<= 1) a += __shfl_xor(a, m);
  if ((threadIdx.x & 63) == 0) red[threadIdx.x >> 6] = a;
  __syncthreads();
  if (threadIdx.x == 0) bias2p[kc] = bias2[kc] + red[0] + red[1];
}

// ---------------- pass C (fp8): logits GEMM + log-softmax + target gather ----------------
__global__ __launch_bounds__(256, 2) void k_passc(
    const unsigned char* __restrict__ H,      // [NROW][NH] fp8
    const unsigned char* __restrict__ L2b8,   // [NCB][CS][HD] fp8 (BN-folded)
    const float* __restrict__ bias2p,         // [NCB][CS]
    const int* __restrict__ ci,
    float* __restrict__ out) {
  __shared__ char smem[64 * 260 * 4];  // 66560B; 3x20480 staging aliased under lg
  __shared__ float red[4];
  float* lg = (float*)smem;            // [64][260]

  const int tid = threadIdx.x, lane = tid & 63, w = tid >> 6;
  const int bidf = blockIdx.y * gridDim.x + blockIdx.x;  // 0..4095
  const int xcd = bidf & 7, p = bidf >> 3;               // p in [0,512)
  const int k = xcd * 2 + (p & 1);
  const int tm = (p >> 1) * 64;
  const int r = lane & 15, hi = lane >> 4;
  const int w64 = tid & ~63;

  auto Asb = [&](int r3) { return (int4v*)(smem + r3 * 20480); };
  auto Bsb = [&](int r3) { return (int4v*)(smem + r3 * 20480 + 4096); };

  auto STAGE = [&](int r3, int kk) {
    const int kb = kk * 64;     // fp8 bytes along K
    {
      const int row = tid >> 2;
      const int pc = (tid & 3) ^ ((row >> 1) & 3);
      gload16(Asb(r3) + w64, H + (size_t)(tm + row) * NH + k * HD + kb + pc * 16);
    }
    #pragma unroll
    for (int i = 0; i < 4; ++i) {
      const int slot = i * 256 + tid;
      const int row = slot >> 2;
      const int pc = (slot & 3) ^ ((row >> 1) & 3);
      gload16(Bsb(r3) + i * 256 + w64,
              L2b8 + (size_t)(k * CS + row) * HD + kb + pc * 16);
    }
  };

  f32x4 acc[4][4] = {};
  STAGE(0, 0);
  STAGE(1, 1);
  asm volatile("s_waitcnt vmcnt(5)" ::: "memory");
  __builtin_amdgcn_s_barrier();

  for (int kk = 0; kk < HD / 64; ++kk) {  // 6 phases
    const int r3 = kk % 3;
    int4v af[4], bfr[4];
    #pragma unroll
    for (int mi = 0; mi < 4; ++mi) {
      const int row = mi * 16 + r;
      af[mi] = Asb(r3)[row * 4 + (hi ^ ((row >> 1) & 3))];
    }
    #pragma unroll
    for (int ni = 0; ni < 4; ++ni) {
      const int row = w * 64 + ni * 16 + r;
      bfr[ni] = Bsb(r3)[row * 4 + (hi ^ ((row >> 1) & 3))];
    }
    if (kk + 2 < HD / 64) STAGE((kk + 2) % 3, kk + 2);
    __builtin_amdgcn_s_setprio(1);
    #pragma unroll
    for (int mi = 0; mi < 4; ++mi) {
      const long a1 = lo64(af[mi]);
      #pragma unroll
      for (int ni = 0; ni < 4; ++ni)
        acc[mi][ni] = __builtin_amdgcn_mfma_f32_16x16x32_fp8_fp8(
            a1, lo64(bfr[ni]), acc[mi][ni], 0, 0, 0);
    }
    #pragma unroll
    for (int mi = 0; mi < 4; ++mi) {
      const long a2 = hi64(af[mi]);
      #pragma unroll
      for (int ni = 0; ni < 4; ++ni)
        acc[mi][ni] = __builtin_amdgcn_mfma_f32_16x16x32_fp8_fp8(
            a2, hi64(bfr[ni]), acc[mi][ni], 0, 0, 0);
    }
    __builtin_amdgcn_s_setprio(0);
    if (kk + 1 < HD / 64) {
      if (kk + 2 < HD / 64) asm volatile("s_waitcnt vmcnt(5)" ::: "memory");
      else                  asm volatile("s_waitcnt vmcnt(0)" ::: "memory");
    }
    __builtin_amdgcn_s_barrier();
  }

  const int lr0 = hi * 4;
  #pragma unroll
  for (int mi = 0; mi < 4; ++mi)
    #pragma unroll
    for (int ni = 0; ni < 4; ++ni) {
      int col = w * 64 + ni * 16 + r;
      float bb = bias2p[k * CS + col];
      #pragma unroll
      for (int reg = 0; reg < 4; ++reg) {
        int row = mi * 16 + lr0 + reg;
        lg[row * 260 + col] = acc[mi][ni][reg] + bb;
      }
    }
  __syncthreads();

  int row = tid >> 2, part = tid & 3;
  const float4* rp = (const float4*)(lg + row * 260 + part * 64);
  float s = 0.f;
  #pragma unroll
  for (int i = 0; i < 16; ++i) {
    float4 v = rp[i];
    s += __expf(v.x) + __expf(v.y) + __expf(v.z) + __expf(v.w);
  }
  s += __shfl_xor(s, 1);
  s += __shfl_xor(s, 2);
  float contrib = 0.f;
  if (part == 0) {
    float lse = __logf(s);
    int c = ci[(size_t)(tm + row) * NCB + k];
    if (c >= 0) {
      c = c < CS ? c : CS - 1;
      contrib = lg[row * 260 + c] - lse;
    }
  }
  #pragma unroll
  for (int msk = 1; msk < 64; msk <<= 1) contrib += __shfl_xor(contrib, msk);
  if (lane == 0) red[w] = contrib;
  __syncthreads();
  if (tid == 0) atomicAdd(out, red[0] + red[1] + red[2] + red[3]);
}

extern "C" void kernel_launch(void* const* d_in, const int* in_sizes, int n_in,
                              void* d_out, int out_size, void* d_ws, size_t ws_size,
                              hipStream_t stream) {
  const float* predictor = (const float*)d_in[0];
  const int* cbidx       = (const int*)d_in[1];
  const float* W1        = (const float*)d_in[2];
  const float* b1        = (const float*)d_in[3];
  const float* lself     = (const float*)d_in[4];
  const float* gamma     = (const float*)d_in[5];
  const float* beta      = (const float*)d_in[6];
  const float* L2        = (const float*)d_in[7];
  const float* bias2     = (const float*)d_in[8];
  float* out = (float*)d_out;

  char* ws = (char*)d_ws;
  size_t off = 0;
  auto alloc = [&](size_t bytes) {
    char* p = ws + off;
    off += (bytes + 255) & ~(size_t)255;
    return p;
  };
  unsigned char* predB8  = (unsigned char*)alloc((size_t)NROW * PD);
  unsigned char* W1B8    = (unsigned char*)alloc((size_t)NH * PD);
  unsigned char* T       = (unsigned char*)alloc((size_t)LSC * LSR);
  unsigned char* H8      = (unsigned char*)alloc((size_t)NROW * NH);
  unsigned char* L2b8    = (unsigned char*)alloc((size_t)NCB * CS * HD);
  float* partials = (float*)alloc((size_t)2 * SA_NBLK * NH * 4);
  float* colsum = (float*)alloc(NH * 4);
  float* colsq  = (float*)alloc(NH * 4);
  float* scale  = (float*)alloc(NH * 4);
  float* shift  = (float*)alloc(NH * 4);
  float* bias2p = (float*)alloc(NCB * CS * 4);

  hipMemsetAsync(d_out, 0, 2 * sizeof(float), stream);
  hipMemsetAsync(colsum, 0, NH * 4, stream);
  hipMemsetAsync(colsq, 0, NH * 4, stream);

  k_f2b8<<<2048, 256, 0, stream>>>(predictor, (unsigned*)predB8, NROW * PD / 8);
  k_f2b8<<<2048, 256, 0, stream>>>(W1, (unsigned*)W1B8, NH * PD / 8);
  k_transpose<<<dim3(LSC / 32, LSR / 32), 256, 0, stream>>>(lself, T);
  k_count<<<NROW / 256, 256, 0, stream>>>(cbidx, out);
  k_gemm1<<<(NROW / 256) * (NH / 128), 512, 0, stream>>>(predB8, W1B8, b1, H8);
  k_selfadd<<<dim3(3, SA_NBLK), 256, 0, stream>>>(H8, T, cbidx, partials);
  k_red<<<dim3(NH / 256, 8), 256, 0, stream>>>(partials, colsum, colsq);
  k_bn<<<NH / 256, 256, 0, stream>>>(colsum, colsq, gamma, beta, scale, shift);
  k_fold<<<NCB * CS, 128, 0, stream>>>(L2, bias2, scale, shift, L2b8, bias2p);
  k_passc<<<dim3(NROW / 64, NCB), 256, 0, stream>>>(H8, L2b8, bias2p, cbidx, out);
}

// Round 21
// 578.194 us; speedup vs baseline: 3.8453x; 3.8453x over previous
//
#include <hip/hip_runtime.h>
#include <hip/hip_bf16.h>

#define NCB 16
#define CS 256
#define HD 384
#define PD 2048
#define NROW 16384
#define NH 6144      // NCB*HD
#define LSR 5760     // (NCB-1)*HD  rows of linear_self
#define LSC 3840     // (NCB-1)*CS  cols of linear_self
#define SA_ROWS 32
#define SA_NBLK (NROW / SA_ROWS)   // 512
#define GK 32                      // 32 K-steps of 64 bytes for fp8 gemm1

typedef __bf16 bf16x8 __attribute__((ext_vector_type(8)));
typedef float f32x4 __attribute__((ext_vector_type(4)));
typedef int int4v __attribute__((ext_vector_type(4)));
typedef int int2v __attribute__((ext_vector_type(2)));

__device__ __forceinline__ unsigned short f2bf(float f) {
  unsigned u = __builtin_bit_cast(unsigned, f);
  u = (u + 0x7fffu + ((u >> 16) & 1u)) >> 16;
  return (unsigned short)u;
}
__device__ __forceinline__ float bf2f(unsigned short h) {
  unsigned u = ((unsigned)h) << 16;
  return __builtin_bit_cast(float, u);
}
__device__ __forceinline__ unsigned char f2fp8(float f) {
  return (unsigned char)__builtin_amdgcn_cvt_pk_fp8_f32(f, f, 0, false);
}
__device__ __forceinline__ long lo64(int4v v) {
  int2v t; t[0] = v[0]; t[1] = v[1];
  return __builtin_bit_cast(long, t);
}
__device__ __forceinline__ long hi64(int4v v) {
  int2v t; t[0] = v[2]; t[1] = v[3];
  return __builtin_bit_cast(long, t);
}

__device__ __forceinline__ void gload16(void* lds, const void* g) {
  __builtin_amdgcn_global_load_lds(
      (const __attribute__((address_space(1))) unsigned int*)g,
      (__attribute__((address_space(3))) unsigned int*)lds, 16, 0, 0);
}

// ---------------- fp32 -> fp8 e4m3 conversion (8 elements/thread/iter) ----------------
__global__ void k_f2b8(const float* __restrict__ in, unsigned* __restrict__ out, int n8) {
  for (int i = blockIdx.x * 256 + threadIdx.x; i < n8; i += gridDim.x * 256) {
    float4 a = ((const float4*)in)[i * 2];
    float4 b = ((const float4*)in)[i * 2 + 1];
    unsigned lo = __builtin_amdgcn_cvt_pk_fp8_f32(a.x, a.y, 0, false);
    lo = __builtin_amdgcn_cvt_pk_fp8_f32(a.z, a.w, lo, true);
    unsigned hi = __builtin_amdgcn_cvt_pk_fp8_f32(b.x, b.y, 0, false);
    hi = __builtin_amdgcn_cvt_pk_fp8_f32(b.z, b.w, hi, true);
    uint2 o = {lo, hi};
    ((uint2*)out)[i] = o;
  }
}

// ---------------- transpose linear_self (5760x3840 f32) -> T (3840x5760 fp8 e4m3) ----------------
__global__ __launch_bounds__(256) void k_transpose(const float* __restrict__ LS,
                                                   unsigned char* __restrict__ T) {
  __shared__ float tile[32][33];
  int tx = threadIdx.x & 31, ty = threadIdx.x >> 5;
  int c0 = blockIdx.x * 32;  // col of LS = row of T
  int r0 = blockIdx.y * 32;  // row of LS = col of T
  for (int i = ty; i < 32; i += 8)
    tile[i][tx] = LS[(size_t)(r0 + i) * LSC + c0 + tx];
  __syncthreads();
  const int i = threadIdx.x >> 3;        // T-row offset 0..31
  const int q = (threadIdx.x & 7) * 4;   // r-offset 0,4,..,28
  unsigned u = __builtin_amdgcn_cvt_pk_fp8_f32(tile[q][i], tile[q + 1][i], 0, false);
  u = __builtin_amdgcn_cvt_pk_fp8_f32(tile[q + 2][i], tile[q + 3][i], u, true);
  *(unsigned*)(T + (size_t)(c0 + i) * LSR + r0 + q) = u;
}

// ---------------- count valid[:,0] ----------------
__global__ void k_count(const int* __restrict__ ci, float* __restrict__ out) {
  int n = blockIdx.x * 256 + threadIdx.x;
  float v = (n < NROW && ci[(size_t)n * NCB] >= 0) ? 1.f : 0.f;
  #pragma unroll
  for (int m = 1; m < 64; m <<= 1) v += __shfl_xor(v, m);
  if ((threadIdx.x & 63) == 0) atomicAdd(out + 1, v);
}

// ---------------- GEMM1 (fp8): 256x128 tile, BK=64, dbuf 48KB, 2 blocks/CU ----------------
// r19 core (proven 378us). Epilogue: acc -> LDS tile (aliases Al after sync)
// -> fully-coalesced 16B/lane NT stores (full 64B lines; kills the 4x write
// amplification of scattered byte stores WITHOUT cached write-allocate).
__global__ __launch_bounds__(512, 4) void k_gemm1(
    const unsigned char* __restrict__ A,   // predictor fp8 [NROW][PD]
    const unsigned char* __restrict__ B,   // W1 fp8 [NH][PD]
    const float* __restrict__ b1,
    unsigned char* __restrict__ H) {       // out [NROW][NH] fp8 (pre-activation)
  __shared__ int4v Al[2][1024];   // [buf][row(256)*4 + pc]  16KB/buf
  __shared__ int4v Bl[2][512];    // [buf][row(128)*4 + pc]   8KB/buf

  const int tid = threadIdx.x;
  const int lane = tid & 63;
  const int w = tid >> 6;             // 0..7
  const int wr = w >> 1, wc = w & 1;  // wave grid 4(M) x 2(N), wave = 64x64
  const int l15 = lane & 15, hi = lane >> 4;
  const int w64 = tid & ~63;

  // XCD swizzle: grid 3072 = 64 mt x 48 nt; each XCD owns 6 nt (1.5MB B -> L2)
  const int bid = blockIdx.x;
  const int xcd = bid & 7, p = bid >> 3;   // p in [0,384)
  const int nt = xcd * 6 + p % 6;
  const int mt = p / 6;
  const int tm = mt * 256, tn = nt * 128;

  f32x4 acc[4][4] = {};

  auto STAGE = [&](int buf, int t) {
    const int kb = t * 64;   // byte offset along K
    #pragma unroll
    for (int g = 0; g < 2; ++g) {   // A: 1024 granules
      const int slot = g * 512 + tid;
      const int row = slot >> 2;
      const int lc = (slot & 3) ^ ((row >> 1) & 3);
      gload16(&Al[buf][g * 512 + w64], A + (size_t)(tm + row) * PD + kb + lc * 16);
    }
    {                                // B: 512 granules
      const int row = tid >> 2;
      const int lc = (tid & 3) ^ ((row >> 1) & 3);
      gload16(&Bl[buf][w64], B + (size_t)(tn + row) * PD + kb + lc * 16);
    }
  };

  STAGE(0, 0);
  asm volatile("s_waitcnt vmcnt(0)" ::: "memory");
  __builtin_amdgcn_s_barrier();

  for (int t = 0; t < GK; ++t) {
    const int buf = t & 1;
    // frag reads (swizzled, b128 = K=64 fp8)
    int4v af[4], bfr[4];
    #pragma unroll
    for (int mi = 0; mi < 4; ++mi) {
      const int row = wr * 64 + mi * 16 + l15;
      af[mi] = Al[buf][row * 4 + (hi ^ ((row >> 1) & 3))];
    }
    #pragma unroll
    for (int ni = 0; ni < 4; ++ni) {
      const int row = wc * 64 + ni * 16 + l15;
      bfr[ni] = Bl[buf][row * 4 + (hi ^ ((row >> 1) & 3))];
    }
    if (t + 1 < GK) STAGE(buf ^ 1, t + 1);   // next-window loads in flight
    // (no barrier here — cross-wave/cross-block read-vs-MFMA overlap)
    __builtin_amdgcn_s_setprio(1);
    #pragma unroll
    for (int mi = 0; mi < 4; ++mi) {
      const long a1 = lo64(af[mi]);
      #pragma unroll
      for (int ni = 0; ni < 4; ++ni)
        acc[mi][ni] = __builtin_amdgcn_mfma_f32_16x16x32_fp8_fp8(
            a1, lo64(bfr[ni]), acc[mi][ni], 0, 0, 0);
    }
    #pragma unroll
    for (int mi = 0; mi < 4; ++mi) {
      const long a2 = hi64(af[mi]);
      #pragma unroll
      for (int ni = 0; ni < 4; ++ni)
        acc[mi][ni] = __builtin_amdgcn_mfma_f32_16x16x32_fp8_fp8(
            a2, hi64(bfr[ni]), acc[mi][ni], 0, 0, 0);
    }
    __builtin_amdgcn_s_setprio(0);
    if (t + 1 < GK) {
      asm volatile("s_waitcnt vmcnt(0)" ::: "memory");
      __builtin_amdgcn_s_barrier();
    }
  }

  // epilogue: bias -> fp8 bytes -> LDS tile (aliases Al; all frag reads done)
  __syncthreads();
  unsigned char* Hs = (unsigned char*)&Al[0][0];   // [256 rows][128 cols] = 32KB
  #pragma unroll
  for (int ni = 0; ni < 4; ++ni) {
    const int col = wc * 64 + ni * 16 + l15;
    const float bb = b1[tn + col];
    #pragma unroll
    for (int mi = 0; mi < 4; ++mi)
      #pragma unroll
      for (int reg = 0; reg < 4; ++reg) {
        const int row = wr * 64 + mi * 16 + hi * 4 + reg;
        Hs[row * 128 + col] = f2fp8(acc[mi][ni][reg] + bb);
      }
  }
  __syncthreads();
  // coalesced NT stores: 2048 16B-granules; 8 threads cover one row's 128B
  #pragma unroll
  for (int it = 0; it < 4; ++it) {
    const int slot = it * 512 + tid;
    const int row = slot >> 3, g = slot & 7;
    int4v v = *(const int4v*)(Hs + row * 128 + g * 16);
    __builtin_nontemporal_store(v, (int4v*)(H + (size_t)(tm + row) * NH + tn + g * 16));
  }
}

// ---------------- self-pred gather: branch-free unrolled, fp8 T + fp8 H ----------------
template <int KM>
__device__ __forceinline__ void gather_chunk(
    const unsigned char* __restrict__ T, const int* idxrow,
    int oo, int bbv, float v[8]) {
  #pragma unroll
  for (int kc = 0; kc < KM; ++kc) {
    int c = idxrow[kc];
    float m = (c >= 0 && kc <= bbv) ? 1.f : 0.f;
    int cc = c < 0 ? 0 : (c >= CS ? CS - 1 : c);
    int2 tv = *(const int2*)(T + (size_t)(kc * CS + cc) * LSR + oo);  // 8 fp8
    float f[8];
    f[0] = __builtin_amdgcn_cvt_f32_fp8(tv.x, 0);
    f[1] = __builtin_amdgcn_cvt_f32_fp8(tv.x, 1);
    f[2] = __builtin_amdgcn_cvt_f32_fp8(tv.x, 2);
    f[3] = __builtin_amdgcn_cvt_f32_fp8(tv.x, 3);
    f[4] = __builtin_amdgcn_cvt_f32_fp8(tv.y, 0);
    f[5] = __builtin_amdgcn_cvt_f32_fp8(tv.y, 1);
    f[6] = __builtin_amdgcn_cvt_f32_fp8(tv.y, 2);
    f[7] = __builtin_amdgcn_cvt_f32_fp8(tv.y, 3);
    #pragma unroll
    for (int e = 0; e < 8; ++e) v[e] = fmaf(m, f[e], v[e]);
  }
}

// grid = dim3(3, SA_NBLK): x = 2048-col stripe, y = 32-row block.
__global__ __launch_bounds__(256) void k_selfadd(
    unsigned char* __restrict__ H,         // [NROW][NH] fp8, in-place
    const unsigned char* __restrict__ T,   // [LSC][LSR] fp8 (linear_self^T)
    const int* __restrict__ ci,
    float* __restrict__ partials) {        // [2][SA_NBLK][NH]
  __shared__ int idxs[SA_ROWS][NCB];
  const int tid = threadIdx.x;
  const int row0 = blockIdx.y * SA_ROWS;
  const int sx = blockIdx.x;               // 0..2, block-uniform
  for (int i = tid; i < SA_ROWS * NCB; i += 256)
    idxs[i >> 4][i & 15] = ci[(size_t)(row0 + (i >> 4)) * NCB + (i & 15)];
  __syncthreads();

  const int col0 = sx * 2048 + tid * 8;
  const int o = col0 - HD;
  const int oo = o < 0 ? 0 : o;
  const int bb = o < 0 ? -1 : o / HD;

  float cs[8] = {0}, cq[8] = {0};

  for (int rr = 0; rr < SA_ROWS; ++rr) {
    const size_t ro = (size_t)(row0 + rr) * NH;
    int2v hv = __builtin_nontemporal_load((const int2v*)(H + ro + col0));
    float v[8];
    v[0] = __builtin_amdgcn_cvt_f32_fp8(hv[0], 0);
    v[1] = __builtin_amdgcn_cvt_f32_fp8(hv[0], 1);
    v[2] = __builtin_amdgcn_cvt_f32_fp8(hv[0], 2);
    v[3] = __builtin_amdgcn_cvt_f32_fp8(hv[0], 3);
    v[4] = __builtin_amdgcn_cvt_f32_fp8(hv[1], 0);
    v[5] = __builtin_amdgcn_cvt_f32_fp8(hv[1], 1);
    v[6] = __builtin_amdgcn_cvt_f32_fp8(hv[1], 2);
    v[7] = __builtin_amdgcn_cvt_f32_fp8(hv[1], 3);
    switch (sx) {
      case 0: gather_chunk<5>(T, idxs[rr], oo, bb, v); break;
      case 1: gather_chunk<10>(T, idxs[rr], oo, bb, v); break;
      default: gather_chunk<15>(T, idxs[rr], oo, bb, v); break;
    }
    float x[8];
    #pragma unroll
    for (int e = 0; e < 8; ++e) x[e] = fmaxf(v[e], 0.f);
    int2v ov;
    unsigned w0 = __builtin_amdgcn_cvt_pk_fp8_f32(x[0], x[1], 0, false);
    w0 = __builtin_amdgcn_cvt_pk_fp8_f32(x[2], x[3], w0, true);
    unsigned w1 = __builtin_amdgcn_cvt_pk_fp8_f32(x[4], x[5], 0, false);
    w1 = __builtin_amdgcn_cvt_pk_fp8_f32(x[6], x[7], w1, true);
    ov[0] = (int)w0; ov[1] = (int)w1;
    float xr0 = __builtin_amdgcn_cvt_f32_fp8(w0, 0);
    float xr1 = __builtin_amdgcn_cvt_f32_fp8(w0, 1);
    float xr2 = __builtin_amdgcn_cvt_f32_fp8(w0, 2);
    float xr3 = __builtin_amdgcn_cvt_f32_fp8(w0, 3);
    float xr4 = __builtin_amdgcn_cvt_f32_fp8(w1, 0);
    float xr5 = __builtin_amdgcn_cvt_f32_fp8(w1, 1);
    float xr6 = __builtin_amdgcn_cvt_f32_fp8(w1, 2);
    float xr7 = __builtin_amdgcn_cvt_f32_fp8(w1, 3);
    cs[0] += xr0; cq[0] += xr0 * xr0;
    cs[1] += xr1; cq[1] += xr1 * xr1;
    cs[2] += xr2; cq[2] += xr2 * xr2;
    cs[3] += xr3; cq[3] += xr3 * xr3;
    cs[4] += xr4; cq[4] += xr4 * xr4;
    cs[5] += xr5; cq[5] += xr5 * xr5;
    cs[6] += xr6; cq[6] += xr6 * xr6;
    cs[7] += xr7; cq[7] += xr7 * xr7;
    __builtin_nontemporal_store(ov, (int2v*)(H + ro + col0));
  }

  float* Ps = partials + (size_t)blockIdx.y * NH + col0;
  float* Pq = partials + (size_t)(SA_NBLK + blockIdx.y) * NH + col0;
  float4 a = {cs[0], cs[1], cs[2], cs[3]};
  float4 b4 = {cs[4], cs[5], cs[6], cs[7]};
  *(float4*)Ps = a; *(float4*)(Ps + 4) = b4;
  float4 c4 = {cq[0], cq[1], cq[2], cq[3]};
  float4 d4 = {cq[4], cq[5], cq[6], cq[7]};
  *(float4*)Pq = c4; *(float4*)(Pq + 4) = d4;
}

// ---------------- reduce partials -> colsum/colsq ----------------
__global__ void k_red(const float* __restrict__ partials,
                      float* __restrict__ colsum, float* __restrict__ colsq) {
  int j = blockIdx.x * 256 + threadIdx.x;
  const float* Ps = partials;
  const float* Pq = partials + (size_t)SA_NBLK * NH;
  float s = 0.f, q = 0.f;
  const int b0 = blockIdx.y * (SA_NBLK / 8), b1 = b0 + SA_NBLK / 8;
  for (int by = b0; by < b1; ++by) {
    s += Ps[(size_t)by * NH + j];
    q += Pq[(size_t)by * NH + j];
  }
  atomicAdd(colsum + j, s);
  atomicAdd(colsq + j, q);
}

// ---------------- BN params ----------------
__global__ void k_bn(const float* __restrict__ colsum, const float* __restrict__ colsq,
                     const float* __restrict__ gamma, const float* __restrict__ beta,
                     float* __restrict__ scale, float* __restrict__ shift) {
  int j = blockIdx.x * 256 + threadIdx.x;
  if (j >= NH) return;
  float mean = colsum[j] * (1.f / NROW);
  float var = colsq[j] * (1.f / NROW) - mean * mean;
  var = fmaxf(var, 0.f);
  float rs = rsqrtf(var + 1e-5f);
  float g = gamma[j] * rs;
  scale[j] = g;
  shift[j] = beta[j] - mean * g;
}

// ---------------- fold BN into linear2/bias2 (fp8 L2b) ----------------
__global__ __launch_bounds__(128) void k_fold(
    const float* __restrict__ L2, const float* __restrict__ bias2,
    const float* __restrict__ scale, const float* __restrict__ shift,
    unsigned char* __restrict__ L2b8, float* __restrict__ bias2p) {
  __shared__ float red[2];
  int kc = blockIdx.x;        // k*256 + c
  int k = kc >> 8;
  size_t off = (size_t)kc * HD;
  float a = 0.f;
  for (int h = threadIdx.x; h < HD; h += 128) {
    float wv = L2[off + h];
    int jh = k * HD + h;
    L2b8[off + h] = f2fp8(wv * scale[jh]);
    a += wv * shift[jh];
  }
  #pragma unroll
  for (int m = 1; m < 64; m <<= 1) a += __shfl_xor(a, m);
  if ((threadIdx.x & 63) == 0) red[threadIdx.x >> 6] = a;
  __syncthreads();
  if (threadIdx.x == 0) bias2p[kc] = bias2[kc] + red[0] + red[1];
}

// ---------------- pass C (fp8): logits GEMM + log-softmax + target gather ----------------
__global__ __launch_bounds__(256, 2) void k_passc(
    const unsigned char* __restrict__ H,      // [NROW][NH] fp8
    const unsigned char* __restrict__ L2b8,   // [NCB][CS][HD] fp8 (BN-folded)
    const float* __restrict__ bias2p,         // [NCB][CS]
    const int* __restrict__ ci,
    float* __restrict__ out) {
  __shared__ char smem[64 * 260 * 4];  // 66560B; 3x20480 staging aliased under lg
  __shared__ float red[4];
  float* lg = (float*)smem;            // [64][260]

  const int tid = threadIdx.x, lane = tid & 63, w = tid >> 6;
  const int bidf = blockIdx.y * gridDim.x + blockIdx.x;  // 0..4095
  const int xcd = bidf & 7, p = bidf >> 3;               // p in [0,512)
  const int k = xcd * 2 + (p & 1);
  const int tm = (p >> 1) * 64;
  const int r = lane & 15, hi = lane >> 4;
  const int w64 = tid & ~63;

  auto Asb = [&](int r3) { return (int4v*)(smem + r3 * 20480); };
  auto Bsb = [&](int r3) { return (int4v*)(smem + r3 * 20480 + 4096); };

  auto STAGE = [&](int r3, int kk) {
    const int kb = kk * 64;     // fp8 bytes along K
    {
      const int row = tid >> 2;
      const int pc = (tid & 3) ^ ((row >> 1) & 3);
      gload16(Asb(r3) + w64, H + (size_t)(tm + row) * NH + k * HD + kb + pc * 16);
    }
    #pragma unroll
    for (int i = 0; i < 4; ++i) {
      const int slot = i * 256 + tid;
      const int row = slot >> 2;
      const int pc = (slot & 3) ^ ((row >> 1) & 3);
      gload16(Bsb(r3) + i * 256 + w64,
              L2b8 + (size_t)(k * CS + row) * HD + kb + pc * 16);
    }
  };

  f32x4 acc[4][4] = {};
  STAGE(0, 0);
  STAGE(1, 1);
  asm volatile("s_waitcnt vmcnt(5)" ::: "memory");
  __builtin_amdgcn_s_barrier();

  for (int kk = 0; kk < HD / 64; ++kk) {  // 6 phases
    const int r3 = kk % 3;
    int4v af[4], bfr[4];
    #pragma unroll
    for (int mi = 0; mi < 4; ++mi) {
      const int row = mi * 16 + r;
      af[mi] = Asb(r3)[row * 4 + (hi ^ ((row >> 1) & 3))];
    }
    #pragma unroll
    for (int ni = 0; ni < 4; ++ni) {
      const int row = w * 64 + ni * 16 + r;
      bfr[ni] = Bsb(r3)[row * 4 + (hi ^ ((row >> 1) & 3))];
    }
    if (kk + 2 < HD / 64) STAGE((kk + 2) % 3, kk + 2);
    __builtin_amdgcn_s_setprio(1);
    #pragma unroll
    for (int mi = 0; mi < 4; ++mi) {
      const long a1 = lo64(af[mi]);
      #pragma unroll
      for (int ni = 0; ni < 4; ++ni)
        acc[mi][ni] = __builtin_amdgcn_mfma_f32_16x16x32_fp8_fp8(
            a1, lo64(bfr[ni]), acc[mi][ni], 0, 0, 0);
    }
    #pragma unroll
    for (int mi = 0; mi < 4; ++mi) {
      const long a2 = hi64(af[mi]);
      #pragma unroll
      for (int ni = 0; ni < 4; ++ni)
        acc[mi][ni] = __builtin_amdgcn_mfma_f32_16x16x32_fp8_fp8(
            a2, hi64(bfr[ni]), acc[mi][ni], 0, 0, 0);
    }
    __builtin_amdgcn_s_setprio(0);
    if (kk + 1 < HD / 64) {
      if (kk + 2 < HD / 64) asm volatile("s_waitcnt vmcnt(5)" ::: "memory");
      else                  asm volatile("s_waitcnt vmcnt(0)" ::: "memory");
    }
    __builtin_amdgcn_s_barrier();
  }

  const int lr0 = hi * 4;
  #pragma unroll
  for (int mi = 0; mi < 4; ++mi)
    #pragma unroll
    for (int ni = 0; ni < 4; ++ni) {
      int col = w * 64 + ni * 16 + r;
      float bb = bias2p[k * CS + col];
      #pragma unroll
      for (int reg = 0; reg < 4; ++reg) {
        int row = mi * 16 + lr0 + reg;
        lg[row * 260 + col] = acc[mi][ni][reg] + bb;
      }
    }
  __syncthreads();

  int row = tid >> 2, part = tid & 3;
  const float4* rp = (const float4*)(lg + row * 260 + part * 64);
  float s = 0.f;
  #pragma unroll
  for (int i = 0; i < 16; ++i) {
    float4 v = rp[i];
    s += __expf(v.x) + __expf(v.y) + __expf(v.z) + __expf(v.w);
  }
  s += __shfl_xor(s, 1);
  s += __shfl_xor(s, 2);
  float contrib = 0.f;
  if (part == 0) {
    float lse = __logf(s);
    int c = ci[(size_t)(tm + row) * NCB + k];
    if (c >= 0) {
      c = c < CS ? c : CS - 1;
      contrib = lg[row * 260 + c] - lse;
    }
  }
  #pragma unroll
  for (int msk = 1; msk < 64; msk <<= 1) contrib += __shfl_xor(contrib, msk);
  if (lane == 0) red[w] = contrib;
  __syncthreads();
  if (tid == 0) atomicAdd(out, red[0] + red[1] + red[2] + red[3]);
}

extern "C" void kernel_launch(void* const* d_in, const int* in_sizes, int n_in,
                              void* d_out, int out_size, void* d_ws, size_t ws_size,
                              hipStream_t stream) {
  const float* predictor = (const float*)d_in[0];
  const int* cbidx       = (const int*)d_in[1];
  const float* W1        = (const float*)d_in[2];
  const float* b1        = (const float*)d_in[3];
  const float* lself     = (const float*)d_in[4];
  const float* gamma     = (const float*)d_in[5];
  const float* beta      = (const float*)d_in[6];
  const float* L2        = (const float*)d_in[7];
  const float* bias2     = (const float*)d_in[8];
  float* out = (float*)d_out;

  char* ws = (char*)d_ws;
  size_t off = 0;
  auto alloc = [&](size_t bytes) {
    char* p = ws + off;
    off += (bytes + 255) & ~(size_t)255;
    return p;
  };
  unsigned char* predB8  = (unsigned char*)alloc((size_t)NROW * PD);
  unsigned char* W1B8    = (unsigned char*)alloc((size_t)NH * PD);
  unsigned char* T       = (unsigned char*)alloc((size_t)LSC * LSR);
  unsigned char* H8      = (unsigned char*)alloc((size_t)NROW * NH);
  unsigned char* L2b8    = (unsigned char*)alloc((size_t)NCB * CS * HD);
  float* partials = (float*)alloc((size_t)2 * SA_NBLK * NH * 4);
  float* colsum = (float*)alloc(NH * 4);
  float* colsq  = (float*)alloc(NH * 4);
  float* scale  = (float*)alloc(NH * 4);
  float* shift  = (float*)alloc(NH * 4);
  float* bias2p = (float*)alloc(NCB * CS * 4);

  hipMemsetAsync(d_out, 0, 2 * sizeof(float), stream);
  hipMemsetAsync(colsum, 0, NH * 4, stream);
  hipMemsetAsync(colsq, 0, NH * 4, stream);

  k_f2b8<<<2048, 256, 0, stream>>>(predictor, (unsigned*)predB8, NROW * PD / 8);
  k_f2b8<<<2048, 256, 0, stream>>>(W1, (unsigned*)W1B8, NH * PD / 8);
  k_transpose<<<dim3(LSC / 32, LSR / 32), 256, 0, stream>>>(lself, T);
  k_count<<<NROW / 256, 256, 0, stream>>>(cbidx, out);
  k_gemm1<<<(NROW / 256) * (NH / 128), 512, 0, stream>>>(predB8, W1B8, b1, H8);
  k_selfadd<<<dim3(3, SA_NBLK), 256, 0, stream>>>(H8, T, cbidx, partials);
  k_red<<<dim3(NH / 256, 8), 256, 0, stream>>>(partials, colsum, colsq);
  k_bn<<<NH / 256, 256, 0, stream>>>(colsum, colsq, gamma, beta, scale, shift);
  k_fold<<<NCB * CS, 128, 0, stream>>>(L2, bias2, scale, shift, L2b8, bias2p);
  k_passc<<<dim3(NROW / 64, NCB), 256, 0, stream>>>(H8, L2b8, bias2p, cbidx, out);
}